// Round 4
// baseline (416.763 us; speedup 1.0000x reference)
//
#include <hip/hip_runtime.h>

// LongformerSelfAttention (B=32,S=512,H=1024,NH=16,HD=64)
// Round 4 = round-3 (passing) + k_gv 2-bn amortization ONLY (round-2's change (c),
// now exonerated: round-2's failure was the view-vs-permute reshape bug in the
// k_qkv transposed epilogue (change (b)), not in k_gv).
// NOTE: reshape(b,NH,s,HD) is a pure VIEW: q[b,n,s,d] = flat[bn*32768 + s*64 + d].
// k_tr implements exactly this view's transpose; do NOT "fix" it to the permute form.
// Pipeline:
//  k_cast : hidden fp32 -> bf16
//  k_wt   : Wq/Wk/Wv (1024x1024) and Wp (1536x512) -> transposed bf16
//  k_qkv  : Q/K/V = hs @ W + b, MFMA 128x128x32 tiles (XCD-swizzled), flat bf16 out
//  k_tr   : per-(b,n) [512][64] -> [64][512] transpose (view-correct d-major)
//  k_gv   : per (bn-pair, s-half): gv GEMM (WpT @ qkvT, K=1536) + sigmoid(q.k/8)
//           blend + gelu + permuted float output. 2 bn per block amortizes WpT staging.

typedef unsigned short ushort_t;
typedef __attribute__((ext_vector_type(8))) short short8;
typedef __attribute__((ext_vector_type(8))) unsigned short ushort8;
typedef __attribute__((ext_vector_type(4))) float f32x4;

#define ASYNC16(gp, lp) __builtin_amdgcn_global_load_lds( \
    (const __attribute__((address_space(1))) void*)(gp),  \
    (__attribute__((address_space(3))) void*)(lp), 16, 0, 0)

__device__ __forceinline__ ushort_t f2b(float f) {
  union { float f; unsigned int u; } v; v.f = f;
  unsigned int r = v.u + 0x7FFFu + ((v.u >> 16) & 1u);
  return (ushort_t)(r >> 16);
}
__device__ __forceinline__ float b2f(ushort_t b) {
  union { unsigned int u; float f; } v; v.u = ((unsigned int)b) << 16;
  return v.f;
}

// ---- workspace layout (bytes), total 142,082,048 ----
#define OFF_HSB 0ull                          // bf16[16384*1024] ; reused as QT after k_qkv
#define OFF_WQT (33554432ull)                 // bf16[1024*1024]  (WqT: [n][k])
#define OFF_WKT (OFF_WQT + 2097152ull)
#define OFF_WVT (OFF_WKT + 2097152ull)
#define OFF_WPT (OFF_WVT + 2097152ull)        // bf16[512*1536]   (WpT: [s][t])
#define OFF_QF  (OFF_WPT + 1572864ull)        // bf16 flat Q ; reused as KT
#define OFF_KF  (OFF_QF + 33554432ull)        // bf16 flat K ; reused as VT
#define OFF_VF  (OFF_KF + 33554432ull)        // bf16 flat V

// ---------------- k_cast: fp32 -> bf16, 8 elems/thread ----------------
extern "C" __global__ __launch_bounds__(256) void k_cast(
    const float* __restrict__ src, ushort_t* __restrict__ dst) {
  int i = blockIdx.x * 256 + threadIdx.x;
  const float4* s = (const float4*)src + (size_t)i * 2;
  float4 a = s[0], b = s[1];
  ushort8 o;
  o[0] = f2b(a.x); o[1] = f2b(a.y); o[2] = f2b(a.z); o[3] = f2b(a.w);
  o[4] = f2b(b.x); o[5] = f2b(b.y); o[6] = f2b(b.z); o[7] = f2b(b.w);
  *((ushort8*)dst + i) = o;
}

// ---------------- k_wt: transpose+cast weights ----------------
extern "C" __global__ __launch_bounds__(256) void k_wt(
    const float* __restrict__ s0, const float* __restrict__ s1,
    const float* __restrict__ s2, const float* __restrict__ s3,
    ushort_t* __restrict__ d0, ushort_t* __restrict__ d1,
    ushort_t* __restrict__ d2, ushort_t* __restrict__ d3) {
  int z = blockIdx.z;
  const float* src = (z == 0) ? s0 : (z == 1) ? s1 : (z == 2) ? s2 : s3;
  ushort_t* dst    = (z == 0) ? d0 : (z == 1) ? d1 : (z == 2) ? d2 : d3;
  int R = (z == 3) ? 1536 : 1024;
  int C = (z == 3) ? 512  : 1024;
  int c0 = blockIdx.x * 64, r0 = blockIdx.y * 64;
  if (c0 >= C || r0 >= R) return;
  __shared__ ushort_t tl[64][80];
  int t = threadIdx.x;
  {
    int lr = t >> 2, cg = (t & 3) * 16;
    const float* sp = src + (size_t)(r0 + lr) * C + c0 + cg;
    #pragma unroll
    for (int i = 0; i < 16; ++i) tl[lr][cg + i] = f2b(sp[i]);
  }
  __syncthreads();
  {
    int lc = t >> 2, rg = (t & 3) * 16;
    ushort_t* dp = dst + (size_t)(c0 + lc) * R + r0 + rg;
    #pragma unroll
    for (int i = 0; i < 16; ++i) dp[i] = tl[rg + i][lc];
  }
}

// ---------------- k_qkv: C = hsb @ W^T(t) + bias, bf16 out ----------------
extern "C" __global__ __launch_bounds__(256) void k_qkv(
    const ushort_t* __restrict__ A,
    const ushort_t* __restrict__ WTq, const ushort_t* __restrict__ WTk, const ushort_t* __restrict__ WTv,
    const float* __restrict__ bq, const float* __restrict__ bk, const float* __restrict__ bv,
    ushort_t* __restrict__ Qf, ushort_t* __restrict__ Kf, ushort_t* __restrict__ Vf) {
  int z = blockIdx.z;
  const ushort_t* WT = (z == 0) ? WTq : (z == 1) ? WTk : WTv;
  const float* bias  = (z == 0) ? bq  : (z == 1) ? bk  : bv;
  ushort_t* out      = (z == 0) ? Qf  : (z == 1) ? Kf  : Vf;

  // XCD-aware bijective remap (1024 blocks, 8 XCDs): each XCD gets a contiguous
  // band of 16 m-tiles (A panel = 4MB = one XCD L2).
  int glin = blockIdx.y * 8 + blockIdx.x;
  int nl = (glin & 7) * 128 + (glin >> 3);
  int n0 = (nl & 7) * 128, m0 = (nl >> 3) * 128;

  __shared__ ushort_t lA[128 * 32];
  __shared__ ushort_t lB[128 * 32];
  int t = threadIdx.x, lane = t & 63, wave = t >> 6;
  int wr = (wave >> 1) * 64, wc = (wave & 1) * 64;

  f32x4 acc[4][4];
  #pragma unroll
  for (int mi = 0; mi < 4; ++mi)
    #pragma unroll
    for (int ni = 0; ni < 4; ++ni)
      acc[mi][ni] = (f32x4){0.f, 0.f, 0.f, 0.f};

  for (int k0 = 0; k0 < 1024; k0 += 32) {
    #pragma unroll
    for (int j = 0; j < 2; ++j) {
      int u = j * 256 + t;
      ASYNC16(A + (size_t)(m0 + (u >> 2)) * 1024 + k0 + (u & 3) * 8,
              (char*)lA + (j * 256 + wave * 64) * 16);
    }
    #pragma unroll
    for (int j = 0; j < 2; ++j) {
      int u = j * 256 + t;
      ASYNC16(WT + (size_t)(n0 + (u >> 2)) * 1024 + k0 + (u & 3) * 8,
              (char*)lB + (j * 256 + wave * 64) * 16);
    }
    __syncthreads();
    short8 af[4], bf[4];
    #pragma unroll
    for (int mi = 0; mi < 4; ++mi)
      af[mi] = *(const short8*)&lA[(wr + mi * 16 + (lane & 15)) * 32 + (lane >> 4) * 8];
    #pragma unroll
    for (int ni = 0; ni < 4; ++ni)
      bf[ni] = *(const short8*)&lB[(wc + ni * 16 + (lane & 15)) * 32 + (lane >> 4) * 8];
    #pragma unroll
    for (int mi = 0; mi < 4; ++mi)
      #pragma unroll
      for (int ni = 0; ni < 4; ++ni)
        acc[mi][ni] = __builtin_amdgcn_mfma_f32_16x16x32_bf16(af[mi], bf[ni], acc[mi][ni], 0, 0, 0);
    __syncthreads();
  }
  #pragma unroll
  for (int ni = 0; ni < 4; ++ni) {
    int gc = n0 + wc + ni * 16 + (lane & 15);
    float bv_ = bias[gc];
    #pragma unroll
    for (int mi = 0; mi < 4; ++mi) {
      int gr = m0 + wr + mi * 16 + ((lane >> 4) << 2);
      #pragma unroll
      for (int r = 0; r < 4; ++r)
        out[(size_t)(gr + r) * 1024 + gc] = f2b(acc[mi][ni][r] + bv_);
    }
  }
}

// ---------------- k_tr: per-(b,n) [512][64] -> [64][512] (view-correct) ----------------
extern "C" __global__ __launch_bounds__(256) void k_tr(
    const ushort_t* __restrict__ src, ushort_t* __restrict__ dst) {
  int bn = blockIdx.x;
  const ushort_t* s = src + (size_t)bn * 32768;
  ushort_t* d = dst + (size_t)bn * 32768;
  __shared__ ushort_t tl[64][80];
  int t = threadIdx.x;
  for (int c = 0; c < 8; ++c) {
    #pragma unroll
    for (int j = 0; j < 2; ++j) {
      int u = j * 256 + t;
      int row = u >> 3, ch = (u & 7) * 8;
      uint4 v = *(const uint4*)&s[(size_t)(c * 64 + row) * 64 + ch];
      const ushort_t* pv = (const ushort_t*)&v;
      #pragma unroll
      for (int i = 0; i < 8; ++i) tl[ch + i][row] = pv[i];
    }
    __syncthreads();
    #pragma unroll
    for (int j = 0; j < 2; ++j) {
      int u = j * 256 + t;
      int dd = u >> 3, ch = (u & 7) * 8;
      *(uint4*)&d[(size_t)dd * 512 + c * 64 + ch] = *(const uint4*)&tl[dd][ch];
    }
    __syncthreads();
  }
}

// ---------------- k_gv: fused gv GEMM + blend + output (2 bn per block) ----------------
// Grid (bng=256, sh=2). Block: 2 bn, C = 256 s x 128 c. 4 waves: wave owns
// (wr = (wave>>1)*128 s-rows) x (bn = bn0 + (wave&1)). K=1536 in 24 steps of 64.
extern "C" __global__ __launch_bounds__(256, 2) void k_gv(
    const ushort_t* __restrict__ WpT,
    const ushort_t* __restrict__ QT, const ushort_t* __restrict__ KT, const ushort_t* __restrict__ VT,
    const float* __restrict__ bp, float* __restrict__ out) {
  int bng = blockIdx.x;            // 0..255
  int sh  = blockIdx.y;            // 0/1
  int s0 = sh * 256;
  int bn0 = bng * 2;
  int t = threadIdx.x, lane = t & 63, wave = t >> 6;
  int wbn = wave & 1;
  int wr  = (wave >> 1) * 128;

  __shared__ ushort_t lA[256 * 64];    // WpT tile [256 s][64 t]
  __shared__ ushort_t lB[2 * 64 * 64]; // per-bn qkvT tile [64 d][64 t]
  __shared__ float p0s[2][256];

  // phase 0: p0 = sigmoid((q.k)/8), coalesced reads from QT/KT (lane -> s)
  if (t < 128) {
    int bnl = t >> 6, qi = t & 63;
    const ushort_t* Qb = QT + (size_t)(bn0 + bnl) * 32768 + s0 + qi * 4;
    const ushort_t* Kb = KT + (size_t)(bn0 + bnl) * 32768 + s0 + qi * 4;
    float dd0 = 0.f, dd1 = 0.f, dd2 = 0.f, dd3 = 0.f;
    #pragma unroll 8
    for (int d = 0; d < 64; ++d) {
      uint2 qv = *(const uint2*)(Qb + (size_t)d * 512);
      uint2 kv = *(const uint2*)(Kb + (size_t)d * 512);
      dd0 += b2f(qv.x & 0xffff) * b2f(kv.x & 0xffff);
      dd1 += b2f(qv.x >> 16)    * b2f(kv.x >> 16);
      dd2 += b2f(qv.y & 0xffff) * b2f(kv.y & 0xffff);
      dd3 += b2f(qv.y >> 16)    * b2f(kv.y >> 16);
    }
    p0s[bnl][qi * 4 + 0] = 1.0f / (1.0f + __expf(-dd0 * 0.125f));
    p0s[bnl][qi * 4 + 1] = 1.0f / (1.0f + __expf(-dd1 * 0.125f));
    p0s[bnl][qi * 4 + 2] = 1.0f / (1.0f + __expf(-dd2 * 0.125f));
    p0s[bnl][qi * 4 + 3] = 1.0f / (1.0f + __expf(-dd3 * 0.125f));
  }

  f32x4 acc[8][4];
  #pragma unroll
  for (int mi = 0; mi < 8; ++mi)
    #pragma unroll
    for (int ni = 0; ni < 4; ++ni)
      acc[mi][ni] = (f32x4){0.f, 0.f, 0.f, 0.f};

  for (int kt = 0; kt < 24; ++kt) {
    int t0 = kt * 64;
    const ushort_t* XT = (t0 < 512) ? QT : (t0 < 1024) ? KT : VT;
    int t0l = t0 & 511;
    #pragma unroll
    for (int j = 0; j < 8; ++j) {        // A: 256x64 = 2048 x16B units
      int uu = j * 256 + t;
      ASYNC16(WpT + (size_t)(s0 + (uu >> 3)) * 1536 + t0 + (uu & 7) * 8,
              (char*)lA + (j * 256 + wave * 64) * 16);
    }
    #pragma unroll
    for (int bl = 0; bl < 2; ++bl) {     // B: 2 x 64x64 = 2 x 512 units
      const ushort_t* Xb = XT + (size_t)(bn0 + bl) * 32768;
      #pragma unroll
      for (int j = 0; j < 2; ++j) {
        int uu = j * 256 + t;
        ASYNC16(Xb + (size_t)(uu >> 3) * 512 + t0l + (uu & 7) * 8,
                (char*)lB + bl * 8192 + (j * 256 + wave * 64) * 16);
      }
    }
    __syncthreads();
    #pragma unroll
    for (int kk = 0; kk < 2; ++kk) {
      short8 bf[4];
      #pragma unroll
      for (int ni = 0; ni < 4; ++ni)
        bf[ni] = *(const short8*)&lB[wbn * 4096 + (ni * 16 + (lane & 15)) * 64 + kk * 32 + (lane >> 4) * 8];
      #pragma unroll
      for (int mi = 0; mi < 8; ++mi) {
        short8 af = *(const short8*)&lA[(wr + mi * 16 + (lane & 15)) * 64 + kk * 32 + (lane >> 4) * 8];
        #pragma unroll
        for (int ni = 0; ni < 4; ++ni)
          acc[mi][ni] = __builtin_amdgcn_mfma_f32_16x16x32_bf16(af, bf[ni], acc[mi][ni], 0, 0, 0);
      }
    }
    __syncthreads();
  }

  // epilogue: ctx = p0*v + (1-p0)*gelu(gv + bp); out[b][s2][nh*64+d] (float)
  int bn = bn0 + wbn;
  int b = bn >> 4, nh = bn & 15;
  const ushort_t* VTb = VT + (size_t)bn * 32768;
  size_t outb = (size_t)b * 512 * 1024 + (size_t)nh * 64;
  #pragma unroll
  for (int mi = 0; mi < 8; ++mi) {
    int sl = wr + mi * 16 + ((lane >> 4) << 2);
    #pragma unroll
    for (int r = 0; r < 4; ++r) {
      int s2 = s0 + sl + r;
      float p0 = p0s[wbn][sl + r];
      float bpv = bp[s2];
      #pragma unroll
      for (int ni = 0; ni < 4; ++ni) {
        int d = ni * 16 + (lane & 15);
        float g = acc[mi][ni][r] + bpv;
        float ge = 0.5f * g * (1.0f + erff(g / 1.41421f));
        float v = b2f(VTb[(size_t)d * 512 + s2]);
        out[outb + (size_t)s2 * 1024 + d] = p0 * v + (1.0f - p0) * ge;
      }
    }
  }
}

extern "C" void kernel_launch(void* const* d_in, const int* in_sizes, int n_in,
                              void* d_out, int out_size, void* d_ws, size_t ws_size,
                              hipStream_t stream) {
  const float* hs = (const float*)d_in[0];
  const float* Wq = (const float*)d_in[1];
  const float* bq = (const float*)d_in[2];
  const float* Wk = (const float*)d_in[3];
  const float* bk = (const float*)d_in[4];
  const float* Wv = (const float*)d_in[5];
  const float* bv = (const float*)d_in[6];
  const float* Wp = (const float*)d_in[7];
  const float* bp = (const float*)d_in[8];

  char* w = (char*)d_ws;
  ushort_t* hsb = (ushort_t*)(w + OFF_HSB);
  ushort_t* WqT = (ushort_t*)(w + OFF_WQT);
  ushort_t* WkT = (ushort_t*)(w + OFF_WKT);
  ushort_t* WvT = (ushort_t*)(w + OFF_WVT);
  ushort_t* WpT = (ushort_t*)(w + OFF_WPT);
  ushort_t* Qf  = (ushort_t*)(w + OFF_QF);
  ushort_t* Kf  = (ushort_t*)(w + OFF_KF);
  ushort_t* Vf  = (ushort_t*)(w + OFF_VF);
  // transposed tensors alias dead buffers (sequential launches keep this safe)
  ushort_t* QTt = (ushort_t*)(w + OFF_HSB);
  ushort_t* KTt = (ushort_t*)(w + OFF_QF);
  ushort_t* VTt = (ushort_t*)(w + OFF_KF);

  k_cast<<<8192, 256, 0, stream>>>(hs, hsb);
  k_wt<<<dim3(16, 24, 4), 256, 0, stream>>>(Wq, Wk, Wv, Wp, WqT, WkT, WvT, WpT);
  k_qkv<<<dim3(8, 128, 3), 256, 0, stream>>>(hsb, WqT, WkT, WvT, bq, bk, bv, Qf, Kf, Vf);
  k_tr<<<512, 256, 0, stream>>>(Qf, QTt);   // QT overwrites hsb (dead after k_qkv)
  k_tr<<<512, 256, 0, stream>>>(Kf, KTt);   // KT overwrites Qf (dead after previous k_tr)
  k_tr<<<512, 256, 0, stream>>>(Vf, VTt);   // VT overwrites Kf
  k_gv<<<dim3(256, 2), 256, 0, stream>>>(WpT, QTt, KTt, VTt, bp, (float*)d_out);
}

// Round 5
// 402.604 us; speedup vs baseline: 1.0352x; 1.0352x over previous
//
#include <hip/hip_runtime.h>

// LongformerSelfAttention (B=32,S=512,H=1024,NH=16,HD=64)
// Round 5 = round-4 with k_gv replaced by a SINGLE regular GEMM (k_gv2) + k_p0.
//   gv[bn,s,d] = sum_t Wp[t,s] * X[bn,t,d]  ==  C[(bn,d)][s] = A[(bn,d)][t] @ WpT[s][t]^T
//   where A row (bn,d) = [QT[bn][d][:], KT[bn][d][:], VT[bn][d][:]]  (t-contiguous,
//   exactly the k_tr outputs). M=32768, N=512, K=1536 — k_qkv skeleton reused.
// NOTE: reshape(b,NH,s,HD) is a pure VIEW: q[b,n,s,d] = flat[bn*32768 + s*64 + d].
// k_tr implements exactly this view's transpose; do NOT "fix" it to the permute form.
// Pipeline:
//  k_cast : hidden fp32 -> bf16
//  k_wt   : Wq/Wk/Wv (1024x1024) and Wp (1536x512) -> transposed bf16
//  k_qkv  : Q/K/V = hs @ W + b, MFMA 128x128x32 tiles (XCD-swizzled), flat bf16 out
//  k_tr   : per-(b,n) [512][64] -> [64][512] transpose (view-correct d-major)
//  k_p0   : p0[bn][s] = sigmoid((q.k)/8)  (f32, into dead Vf region)
//  k_gv2  : 32768x512x1536 GEMM + blend(p0,v) + gelu + permuted float output

typedef unsigned short ushort_t;
typedef __attribute__((ext_vector_type(8))) short short8;
typedef __attribute__((ext_vector_type(8))) unsigned short ushort8;
typedef __attribute__((ext_vector_type(4))) float f32x4;

#define ASYNC16(gp, lp) __builtin_amdgcn_global_load_lds( \
    (const __attribute__((address_space(1))) void*)(gp),  \
    (__attribute__((address_space(3))) void*)(lp), 16, 0, 0)

__device__ __forceinline__ ushort_t f2b(float f) {
  union { float f; unsigned int u; } v; v.f = f;
  unsigned int r = v.u + 0x7FFFu + ((v.u >> 16) & 1u);
  return (ushort_t)(r >> 16);
}
__device__ __forceinline__ float b2f(ushort_t b) {
  union { unsigned int u; float f; } v; v.u = ((unsigned int)b) << 16;
  return v.f;
}

// ---- workspace layout (bytes), total 142,082,048 ----
#define OFF_HSB 0ull                          // bf16[16384*1024] ; reused as QT after k_qkv
#define OFF_WQT (33554432ull)                 // bf16[1024*1024]  (WqT: [n][k])
#define OFF_WKT (OFF_WQT + 2097152ull)
#define OFF_WVT (OFF_WKT + 2097152ull)
#define OFF_WPT (OFF_WVT + 2097152ull)        // bf16[512*1536]   (WpT: [s][t])
#define OFF_QF  (OFF_WPT + 1572864ull)        // bf16 flat Q ; reused as KT
#define OFF_KF  (OFF_QF + 33554432ull)        // bf16 flat K ; reused as VT
#define OFF_VF  (OFF_KF + 33554432ull)        // bf16 flat V ; reused as p0buf (f32[512*512])

// ---------------- k_cast: fp32 -> bf16, 8 elems/thread ----------------
extern "C" __global__ __launch_bounds__(256) void k_cast(
    const float* __restrict__ src, ushort_t* __restrict__ dst) {
  int i = blockIdx.x * 256 + threadIdx.x;
  const float4* s = (const float4*)src + (size_t)i * 2;
  float4 a = s[0], b = s[1];
  ushort8 o;
  o[0] = f2b(a.x); o[1] = f2b(a.y); o[2] = f2b(a.z); o[3] = f2b(a.w);
  o[4] = f2b(b.x); o[5] = f2b(b.y); o[6] = f2b(b.z); o[7] = f2b(b.w);
  *((ushort8*)dst + i) = o;
}

// ---------------- k_wt: transpose+cast weights ----------------
extern "C" __global__ __launch_bounds__(256) void k_wt(
    const float* __restrict__ s0, const float* __restrict__ s1,
    const float* __restrict__ s2, const float* __restrict__ s3,
    ushort_t* __restrict__ d0, ushort_t* __restrict__ d1,
    ushort_t* __restrict__ d2, ushort_t* __restrict__ d3) {
  int z = blockIdx.z;
  const float* src = (z == 0) ? s0 : (z == 1) ? s1 : (z == 2) ? s2 : s3;
  ushort_t* dst    = (z == 0) ? d0 : (z == 1) ? d1 : (z == 2) ? d2 : d3;
  int R = (z == 3) ? 1536 : 1024;
  int C = (z == 3) ? 512  : 1024;
  int c0 = blockIdx.x * 64, r0 = blockIdx.y * 64;
  if (c0 >= C || r0 >= R) return;
  __shared__ ushort_t tl[64][80];
  int t = threadIdx.x;
  {
    int lr = t >> 2, cg = (t & 3) * 16;
    const float* sp = src + (size_t)(r0 + lr) * C + c0 + cg;
    #pragma unroll
    for (int i = 0; i < 16; ++i) tl[lr][cg + i] = f2b(sp[i]);
  }
  __syncthreads();
  {
    int lc = t >> 2, rg = (t & 3) * 16;
    ushort_t* dp = dst + (size_t)(c0 + lc) * R + r0 + rg;
    #pragma unroll
    for (int i = 0; i < 16; ++i) dp[i] = tl[rg + i][lc];
  }
}

// ---------------- k_qkv: C = hsb @ W^T(t) + bias, bf16 out ----------------
extern "C" __global__ __launch_bounds__(256) void k_qkv(
    const ushort_t* __restrict__ A,
    const ushort_t* __restrict__ WTq, const ushort_t* __restrict__ WTk, const ushort_t* __restrict__ WTv,
    const float* __restrict__ bq, const float* __restrict__ bk, const float* __restrict__ bv,
    ushort_t* __restrict__ Qf, ushort_t* __restrict__ Kf, ushort_t* __restrict__ Vf) {
  int z = blockIdx.z;
  const ushort_t* WT = (z == 0) ? WTq : (z == 1) ? WTk : WTv;
  const float* bias  = (z == 0) ? bq  : (z == 1) ? bk  : bv;
  ushort_t* out      = (z == 0) ? Qf  : (z == 1) ? Kf  : Vf;

  // XCD-aware bijective remap (1024 blocks, 8 XCDs): each XCD gets a contiguous
  // band of 16 m-tiles (A panel = 4MB = one XCD L2).
  int glin = blockIdx.y * 8 + blockIdx.x;
  int nl = (glin & 7) * 128 + (glin >> 3);
  int n0 = (nl & 7) * 128, m0 = (nl >> 3) * 128;

  __shared__ ushort_t lA[128 * 32];
  __shared__ ushort_t lB[128 * 32];
  int t = threadIdx.x, lane = t & 63, wave = t >> 6;
  int wr = (wave >> 1) * 64, wc = (wave & 1) * 64;

  f32x4 acc[4][4];
  #pragma unroll
  for (int mi = 0; mi < 4; ++mi)
    #pragma unroll
    for (int ni = 0; ni < 4; ++ni)
      acc[mi][ni] = (f32x4){0.f, 0.f, 0.f, 0.f};

  for (int k0 = 0; k0 < 1024; k0 += 32) {
    #pragma unroll
    for (int j = 0; j < 2; ++j) {
      int u = j * 256 + t;
      ASYNC16(A + (size_t)(m0 + (u >> 2)) * 1024 + k0 + (u & 3) * 8,
              (char*)lA + (j * 256 + wave * 64) * 16);
    }
    #pragma unroll
    for (int j = 0; j < 2; ++j) {
      int u = j * 256 + t;
      ASYNC16(WT + (size_t)(n0 + (u >> 2)) * 1024 + k0 + (u & 3) * 8,
              (char*)lB + (j * 256 + wave * 64) * 16);
    }
    __syncthreads();
    short8 af[4], bf[4];
    #pragma unroll
    for (int mi = 0; mi < 4; ++mi)
      af[mi] = *(const short8*)&lA[(wr + mi * 16 + (lane & 15)) * 32 + (lane >> 4) * 8];
    #pragma unroll
    for (int ni = 0; ni < 4; ++ni)
      bf[ni] = *(const short8*)&lB[(wc + ni * 16 + (lane & 15)) * 32 + (lane >> 4) * 8];
    #pragma unroll
    for (int mi = 0; mi < 4; ++mi)
      #pragma unroll
      for (int ni = 0; ni < 4; ++ni)
        acc[mi][ni] = __builtin_amdgcn_mfma_f32_16x16x32_bf16(af[mi], bf[ni], acc[mi][ni], 0, 0, 0);
    __syncthreads();
  }
  #pragma unroll
  for (int ni = 0; ni < 4; ++ni) {
    int gc = n0 + wc + ni * 16 + (lane & 15);
    float bv_ = bias[gc];
    #pragma unroll
    for (int mi = 0; mi < 4; ++mi) {
      int gr = m0 + wr + mi * 16 + ((lane >> 4) << 2);
      #pragma unroll
      for (int r = 0; r < 4; ++r)
        out[(size_t)(gr + r) * 1024 + gc] = f2b(acc[mi][ni][r] + bv_);
    }
  }
}

// ---------------- k_tr: per-(b,n) [512][64] -> [64][512] (view-correct) ----------------
extern "C" __global__ __launch_bounds__(256) void k_tr(
    const ushort_t* __restrict__ src, ushort_t* __restrict__ dst) {
  int bn = blockIdx.x;
  const ushort_t* s = src + (size_t)bn * 32768;
  ushort_t* d = dst + (size_t)bn * 32768;
  __shared__ ushort_t tl[64][80];
  int t = threadIdx.x;
  for (int c = 0; c < 8; ++c) {
    #pragma unroll
    for (int j = 0; j < 2; ++j) {
      int u = j * 256 + t;
      int row = u >> 3, ch = (u & 7) * 8;
      uint4 v = *(const uint4*)&s[(size_t)(c * 64 + row) * 64 + ch];
      const ushort_t* pv = (const ushort_t*)&v;
      #pragma unroll
      for (int i = 0; i < 8; ++i) tl[ch + i][row] = pv[i];
    }
    __syncthreads();
    #pragma unroll
    for (int j = 0; j < 2; ++j) {
      int u = j * 256 + t;
      int dd = u >> 3, ch = (u & 7) * 8;
      *(uint4*)&d[(size_t)dd * 512 + c * 64 + ch] = *(const uint4*)&tl[dd][ch];
    }
    __syncthreads();
  }
}

// ---------------- k_p0: p0[bn][s] = sigmoid((q.k)/8) ----------------
extern "C" __global__ __launch_bounds__(256) void k_p0(
    const ushort_t* __restrict__ QT, const ushort_t* __restrict__ KT,
    float* __restrict__ p0buf) {
  int bn = blockIdx.x;
  int t = threadIdx.x;
  const ushort_t* Qb = QT + (size_t)bn * 32768;
  const ushort_t* Kb = KT + (size_t)bn * 32768;
  #pragma unroll
  for (int sc = 0; sc < 2; ++sc) {
    int s = sc * 256 + t;
    float dot = 0.f;
    #pragma unroll 8
    for (int d = 0; d < 64; ++d)
      dot += b2f(Qb[d * 512 + s]) * b2f(Kb[d * 512 + s]);
    p0buf[bn * 512 + s] = 1.0f / (1.0f + __expf(-dot * 0.125f));
  }
}

// ---------------- k_gv2: C[(bn,d)][s] = A @ WpT^T, fused blend epilogue ----------------
// M=32768 (row=(bn,d)), N=512 (col=s), K=1536 (t: 0-511=Q, 512-1023=K, 1024-1535=V).
// A row (bn,d), K-chunk seg/kk: XT[bn*32768 + d*512 + kk] (t-contiguous). B = WpT[s][t].
// 128x128 tile, BK=32, 48 K-steps. XCD swizzle: contiguous 32-mt band/XCD, nt fastest.
extern "C" __global__ __launch_bounds__(256) void k_gv2(
    const ushort_t* __restrict__ QT, const ushort_t* __restrict__ KT, const ushort_t* __restrict__ VT,
    const ushort_t* __restrict__ WpT, const float* __restrict__ p0buf,
    const float* __restrict__ bp, float* __restrict__ out) {
  int glin = blockIdx.y * 8 + blockIdx.x;        // 0..1023
  int nl = (glin & 7) * 128 + (glin >> 3);       // xcd-contiguous band
  int mt = nl >> 2, nt = nl & 3;                 // 256 m-tiles x 4 n-tiles
  int m0 = mt * 128, n0 = nt * 128;

  __shared__ ushort_t lA[128 * 32];
  __shared__ ushort_t lB[128 * 32];
  int t = threadIdx.x, lane = t & 63, wave = t >> 6;
  int wr = (wave >> 1) * 64, wc = (wave & 1) * 64;

  f32x4 acc[4][4];
  #pragma unroll
  for (int mi = 0; mi < 4; ++mi)
    #pragma unroll
    for (int ni = 0; ni < 4; ++ni)
      acc[mi][ni] = (f32x4){0.f, 0.f, 0.f, 0.f};

  for (int seg = 0; seg < 3; ++seg) {
    const ushort_t* XT = (seg == 0) ? QT : (seg == 1) ? KT : VT;
    for (int kk = 0; kk < 512; kk += 32) {
      int k0 = seg * 512 + kk;
      #pragma unroll
      for (int j = 0; j < 2; ++j) {      // A: 128 rows x 32 t
        int u = j * 256 + t;
        int ar = m0 + (u >> 2);
        ASYNC16(XT + ((size_t)(ar >> 6) << 15) + (size_t)(ar & 63) * 512 + kk + (u & 3) * 8,
                (char*)lA + (j * 256 + wave * 64) * 16);
      }
      #pragma unroll
      for (int j = 0; j < 2; ++j) {      // B: 128 s-rows x 32 t
        int u = j * 256 + t;
        ASYNC16(WpT + (size_t)(n0 + (u >> 2)) * 1536 + k0 + (u & 3) * 8,
                (char*)lB + (j * 256 + wave * 64) * 16);
      }
      __syncthreads();
      short8 af[4], bf[4];
      #pragma unroll
      for (int mi = 0; mi < 4; ++mi)
        af[mi] = *(const short8*)&lA[(wr + mi * 16 + (lane & 15)) * 32 + (lane >> 4) * 8];
      #pragma unroll
      for (int ni = 0; ni < 4; ++ni)
        bf[ni] = *(const short8*)&lB[(wc + ni * 16 + (lane & 15)) * 32 + (lane >> 4) * 8];
      #pragma unroll
      for (int mi = 0; mi < 4; ++mi)
        #pragma unroll
        for (int ni = 0; ni < 4; ++ni)
          acc[mi][ni] = __builtin_amdgcn_mfma_f32_16x16x32_bf16(af[mi], bf[ni], acc[mi][ni], 0, 0, 0);
      __syncthreads();
    }
  }

  // epilogue: row gr=(bn,d), col gc=s; ctx = p0*v + (1-p0)*gelu(gv + bp);
  // out[b][s][nh*64+d] -> 4 consecutive d per fragment = aligned float4 store.
  #pragma unroll
  for (int mi = 0; mi < 4; ++mi) {
    int r0 = m0 + wr + mi * 16 + ((lane >> 4) << 2);
    int bn = r0 >> 6, d0 = r0 & 63;
    int b = bn >> 4, nh = bn & 15;
    const ushort_t* VTb = VT + ((size_t)bn << 15);
    const float* p0row = p0buf + bn * 512;
    size_t outb = (size_t)b * 524288 + (size_t)nh * 64 + d0;
    #pragma unroll
    for (int ni = 0; ni < 4; ++ni) {
      int gc = n0 + wc + ni * 16 + (lane & 15);   // s
      float p0 = p0row[gc];
      float bpv = bp[gc];
      float4 o;
      #pragma unroll
      for (int r = 0; r < 4; ++r) {
        float g = acc[mi][ni][r] + bpv;
        float ge = 0.5f * g * (1.0f + erff(g / 1.41421f));
        float v = b2f(VTb[(size_t)(d0 + r) * 512 + gc]);
        ((float*)&o)[r] = p0 * v + (1.0f - p0) * ge;
      }
      *(float4*)&out[outb + (size_t)gc * 1024] = o;
    }
  }
}

extern "C" void kernel_launch(void* const* d_in, const int* in_sizes, int n_in,
                              void* d_out, int out_size, void* d_ws, size_t ws_size,
                              hipStream_t stream) {
  const float* hs = (const float*)d_in[0];
  const float* Wq = (const float*)d_in[1];
  const float* bq = (const float*)d_in[2];
  const float* Wk = (const float*)d_in[3];
  const float* bk = (const float*)d_in[4];
  const float* Wv = (const float*)d_in[5];
  const float* bv = (const float*)d_in[6];
  const float* Wp = (const float*)d_in[7];
  const float* bp = (const float*)d_in[8];

  char* w = (char*)d_ws;
  ushort_t* hsb = (ushort_t*)(w + OFF_HSB);
  ushort_t* WqT = (ushort_t*)(w + OFF_WQT);
  ushort_t* WkT = (ushort_t*)(w + OFF_WKT);
  ushort_t* WvT = (ushort_t*)(w + OFF_WVT);
  ushort_t* WpT = (ushort_t*)(w + OFF_WPT);
  ushort_t* Qf  = (ushort_t*)(w + OFF_QF);
  ushort_t* Kf  = (ushort_t*)(w + OFF_KF);
  ushort_t* Vf  = (ushort_t*)(w + OFF_VF);
  // aliases over dead buffers (sequential launches keep this safe):
  ushort_t* QTt = (ushort_t*)(w + OFF_HSB);  // QT overwrites hsb (dead after k_qkv)
  ushort_t* KTt = (ushort_t*)(w + OFF_QF);   // KT overwrites Qf  (dead after k_tr #1)
  ushort_t* VTt = (ushort_t*)(w + OFF_KF);   // VT overwrites Kf  (dead after k_tr #2)
  float*    p0b = (float*)(w + OFF_VF);      // p0 overwrites Vf  (dead after k_tr #3)

  k_cast<<<8192, 256, 0, stream>>>(hs, hsb);
  k_wt<<<dim3(16, 24, 4), 256, 0, stream>>>(Wq, Wk, Wv, Wp, WqT, WkT, WvT, WpT);
  k_qkv<<<dim3(8, 128, 3), 256, 0, stream>>>(hsb, WqT, WkT, WvT, bq, bk, bv, Qf, Kf, Vf);
  k_tr<<<512, 256, 0, stream>>>(Qf, QTt);
  k_tr<<<512, 256, 0, stream>>>(Kf, KTt);
  k_tr<<<512, 256, 0, stream>>>(Vf, VTt);
  k_p0<<<512, 256, 0, stream>>>(QTt, KTt, p0b);
  k_gv2<<<dim3(8, 128), 256, 0, stream>>>(QTt, KTt, VTt, WpT, p0b, bp, (float*)d_out);
}